// Round 1
// baseline (298.557 us; speedup 1.0000x reference)
//
#include <hip/hip_runtime.h>
#include <hip/hip_bf16.h>

typedef __attribute__((ext_vector_type(8))) short short8;
typedef __attribute__((ext_vector_type(4))) float f32x4;

#define NB 8
#define NC 256
#define NNN 4096

__device__ __forceinline__ ushort f2bf(float f) {
  __hip_bfloat16 h = __float2bfloat16(f);
  return *reinterpret_cast<ushort*>(&h);
}

// fT[b][n][c] = bf16(x[b][c][n])
__global__ __launch_bounds__(256) void prep_kernel(const float* __restrict__ x,
                                                   ushort* __restrict__ fT) {
  __shared__ float tile[32][33];
  const int tx = threadIdx.x, ty = threadIdx.y;
  const int n0 = blockIdx.x * 32, c0 = blockIdx.y * 32, b = blockIdx.z;
#pragma unroll
  for (int k = 0; k < 4; ++k) {
    tile[ty + 8 * k][tx] =
        x[((size_t)(b * NC + c0 + ty + 8 * k)) * NNN + n0 + tx];
  }
  __syncthreads();
#pragma unroll
  for (int k = 0; k < 4; ++k) {
    int n = n0 + ty + 8 * k;
    fT[((size_t)(b * NNN + n)) * NC + c0 + tx] = f2bf(tile[tx][ty + 8 * k]);
  }
}

__global__ __launch_bounds__(256, 2) void attn_kernel(
    const float* __restrict__ x, const ushort* __restrict__ fT,
    const float* __restrict__ gamma, float* __restrict__ out) {
  __shared__ union U {
    struct {
      ushort Kt[64][264];   // [m][c], +8 pad
      ushort Vt[256][72];   // [c][m], +8 pad
      ushort Pw[4][16][72]; // per-wave P, [n][m], +8 pad
    } a;
    float ot[4][256 * 17];  // epilogue transpose [c][n], +1 pad
  } sm __attribute__((aligned(16)));

  const int tid = threadIdx.x;
  const int wave = tid >> 6;
  const int lane = tid & 63;
  const int g = lane >> 4;
  const int r = lane & 15;
  const int b = blockIdx.x & 7;            // batch -> XCD
  const int n0 = (blockIdx.x >> 3) << 6;   // 64 query rows per block

  const ushort* fTb = fT + (size_t)b * NNN * NC;
  const float* xb = x + (size_t)b * NC * NNN;

  // Q fragments resident in registers: row n0+wave*16+r, k = kf*32+8g+i
  short8 q[8];
  {
    const ushort* qp = fTb + (size_t)(n0 + wave * 16 + r) * NC + 8 * g;
#pragma unroll
    for (int kf = 0; kf < 8; ++kf) q[kf] = *(const short8*)(qp + kf * 32);
  }

  f32x4 o[16];
#pragma unroll
  for (int cf = 0; cf < 16; ++cf) o[cf] = (f32x4){0.f, 0.f, 0.f, 0.f};
  float m_run[4] = {-3e38f, -3e38f, -3e38f, -3e38f};
  float l_run[4] = {0.f, 0.f, 0.f, 0.f};
  const float L2E = 1.44269504088896f;

  for (int mt = 0; mt < NNN / 64; ++mt) {
    const int m0 = mt * 64;
    __syncthreads();
    // stage Kt[64][256] <- fT[b][m0+row][:]
    {
      const int row = tid >> 5;
      const int col = (tid & 31) * 8;
#pragma unroll
      for (int p = 0; p < 8; ++p)
        *(short8*)&sm.a.Kt[row + 8 * p][col] =
            *(const short8*)(fTb + (size_t)(m0 + row + 8 * p) * NC + col);
    }
    // stage Vt[256][64] <- bf16(x[b][c][m0+m])
    {
      const int row = tid >> 3;
      const int col = (tid & 7) * 8;
#pragma unroll
      for (int p = 0; p < 8; ++p) {
        const float* src = xb + (size_t)(row + 32 * p) * NNN + m0 + col;
        f32x4 v0 = *(const f32x4*)src;
        f32x4 v1 = *(const f32x4*)(src + 4);
        short8 w;
        w[0] = (short)f2bf(v0[0]); w[1] = (short)f2bf(v0[1]);
        w[2] = (short)f2bf(v0[2]); w[3] = (short)f2bf(v0[3]);
        w[4] = (short)f2bf(v1[0]); w[5] = (short)f2bf(v1[1]);
        w[6] = (short)f2bf(v1[2]); w[7] = (short)f2bf(v1[3]);
        *(short8*)&sm.a.Vt[row + 32 * p][col] = w;
      }
    }
    __syncthreads();

    // S = Q K^T  (S[mf]: col m = m0+mf*16+r, row n = n0+wave*16+4g+i)
    f32x4 s[4];
#pragma unroll
    for (int mf = 0; mf < 4; ++mf) s[mf] = (f32x4){0.f, 0.f, 0.f, 0.f};
#pragma unroll
    for (int kc = 0; kc < 8; ++kc) {
#pragma unroll
      for (int mf = 0; mf < 4; ++mf) {
        short8 kb = *(const short8*)&sm.a.Kt[mf * 16 + r][kc * 32 + 8 * g];
        s[mf] = __builtin_amdgcn_mfma_f32_16x16x32_bf16(q[kc], kb, s[mf], 0, 0, 0);
      }
    }

    // online softmax over m (cols): reduce across the 16 lanes of group g
    float scale[4], rsum[4];
#pragma unroll
    for (int i = 0; i < 4; ++i) {
      float rm = fmaxf(fmaxf(s[0][i], s[1][i]), fmaxf(s[2][i], s[3][i]));
#pragma unroll
      for (int off = 1; off < 16; off <<= 1)
        rm = fmaxf(rm, __shfl_xor(rm, off));
      float mn = fmaxf(m_run[i], rm);
      scale[i] = exp2f((m_run[i] - mn) * L2E);
      m_run[i] = mn;
      rsum[i] = 0.f;
    }
#pragma unroll
    for (int mf = 0; mf < 4; ++mf) {
#pragma unroll
      for (int i = 0; i < 4; ++i) {
        float p = exp2f((s[mf][i] - m_run[i]) * L2E);
        s[mf][i] = p;
        rsum[i] += p;
      }
    }
#pragma unroll
    for (int i = 0; i < 4; ++i) {
      float rs = rsum[i];
#pragma unroll
      for (int off = 1; off < 16; off <<= 1) rs += __shfl_xor(rs, off);
      l_run[i] = l_run[i] * scale[i] + rs;
    }
    f32x4 sc = (f32x4){scale[0], scale[1], scale[2], scale[3]};
#pragma unroll
    for (int cf = 0; cf < 16; ++cf) o[cf] *= sc;

    // P (D-layout) -> per-wave LDS -> A-layout
#pragma unroll
    for (int mf = 0; mf < 4; ++mf)
#pragma unroll
      for (int i = 0; i < 4; ++i)
        sm.a.Pw[wave][4 * g + i][mf * 16 + r] = f2bf(s[mf][i]);

    // O += P V
#pragma unroll
    for (int ks = 0; ks < 2; ++ks) {
      short8 pa = *(const short8*)&sm.a.Pw[wave][r][ks * 32 + 8 * g];
#pragma unroll
      for (int cf = 0; cf < 16; ++cf) {
        short8 vb = *(const short8*)&sm.a.Vt[cf * 16 + r][ks * 32 + 8 * g];
        o[cf] = __builtin_amdgcn_mfma_f32_16x16x32_bf16(pa, vb, o[cf], 0, 0, 0);
      }
    }
  }

  __syncthreads();  // all waves done with Kt/Vt/Pw before ot overlay

  // epilogue: normalize, transpose via LDS, out = gamma*O + x (coalesced)
  float linv[4];
#pragma unroll
  for (int i = 0; i < 4; ++i) linv[i] = 1.0f / l_run[i];
  float* ot = sm.ot[wave];
#pragma unroll
  for (int cf = 0; cf < 16; ++cf)
#pragma unroll
    for (int i = 0; i < 4; ++i)
      ot[(cf * 16 + r) * 17 + 4 * g + i] = o[cf][i] * linv[i];
  // ot is wave-private; compiler inserts lgkmcnt waits for the RAW hazard.
  const float gam = gamma[0];
#pragma unroll
  for (int k = 0; k < 16; ++k) {
    const int c = k * 16 + (lane >> 2);
    const int nn = (lane & 3) * 4;
    const size_t gi = ((size_t)(b * NC + c)) * NNN + n0 + wave * 16 + nn;
    f32x4 xv = *(const f32x4*)(x + gi);
    f32x4 ov;
#pragma unroll
    for (int j = 0; j < 4; ++j) ov[j] = ot[c * 17 + nn + j];
    *(f32x4*)(out + gi) = gam * ov + xv;
  }
}

extern "C" void kernel_launch(void* const* d_in, const int* in_sizes, int n_in,
                              void* d_out, int out_size, void* d_ws,
                              size_t ws_size, hipStream_t stream) {
  const float* x = (const float*)d_in[0];
  const float* gamma = (const float*)d_in[1];
  float* out = (float*)d_out;
  ushort* fT = (ushort*)d_ws;  // 8*4096*256*2 = 16.78 MB

  dim3 pg(NNN / 32, NC / 32, NB);
  dim3 pb(32, 8, 1);
  prep_kernel<<<pg, pb, 0, stream>>>(x, fT);

  attn_kernel<<<dim3(NB * (NNN / 64)), dim3(256), 0, stream>>>(x, fT, gamma, out);
}